// Round 5
// baseline (1426.138 us; speedup 1.0000x reference)
//
#include <hip/hip_runtime.h>

#define NB 4096
#define NT 256

typedef float f32x2 __attribute__((ext_vector_type(2)));

// One wave = TWO chains (chain A in .x, chain B in .y of f32x2 values).
// CDNA4 v_pk_fma_f32 is full-rate -> per-chain VALU halves vs 1-chain/wave.
// Lane h owns hidden unit h. W2 pairs {w[2m],w[2m+1]} per lane = 64 VGPRs.
// h1 stored chain-separated in LDS so layer2 pk ops pair consecutive j of
// one chain (weight operand is a natural register pair, no splat movs).
// waves_per_eu(2,4): min-occupancy 2 -> 256-VGPR arch budget -> no AGPR
// spill copies (round 2-4: 64 arch VGPR cap put w2r in AGPRs, ~2x layer2).

template <int ctrl, int rm, int bm>
__device__ __forceinline__ float dpp_add(float v) {
    int m = __builtin_amdgcn_update_dpp(0, __builtin_bit_cast(int, v),
                                        ctrl, rm, bm, true);
    return v + __builtin_bit_cast(float, m);
}

__device__ __forceinline__ float rl63(float v) {
    return __builtin_bit_cast(float,
        __builtin_amdgcn_readlane(__builtin_bit_cast(int, v), 63));
}

__global__ __attribute__((amdgpu_flat_work_group_size(256, 256),
                          amdgpu_waves_per_eu(2, 4)))
void tworeac_kernel(
    const float* __restrict__ u, const float* __restrict__ yseq,
    const float* __restrict__ useq, const float* __restrict__ W1,
    const float* __restrict__ b1, const float* __restrict__ W2,
    const float* __restrict__ b2, const float* __restrict__ W3,
    const float* __restrict__ b3, float* __restrict__ out)
{
    const int lane = threadIdx.x & 63;
    const int wave = threadIdx.x >> 6;
    const int cA = (blockIdx.x * 4 + wave) * 2;
    const int cB = cA + 1;

    __shared__ float h1A[4][64];
    __shared__ float h1B[4][64];

    // ---- weights into registers (lane owns hidden column h = lane) ----
    f32x2 w2p[32];
    #pragma unroll
    for (int m = 0; m < 32; ++m)
        w2p[m] = (f32x2){W2[(2 * m) * 64 + lane], W2[(2 * m + 1) * 64 + lane]};
    float w1x[3], w1y[9], w1u[3], w3r[3];
    #pragma unroll
    for (int i = 0; i < 3; ++i) w1x[i] = W1[i * 64 + lane];
    #pragma unroll
    for (int i = 0; i < 9; ++i) w1y[i] = W1[(3 + i) * 64 + lane];
    #pragma unroll
    for (int i = 0; i < 3; ++i) w1u[i] = W1[(12 + i) * 64 + lane];
    #pragma unroll
    for (int k = 0; k < 3; ++k) w3r[k] = W3[lane * 3 + k];
    const float b1h = b1[lane];
    const float b2h = b2[lane];
    const float b30 = b3[0], b31 = b3[1], b32 = b3[2];

    const float* uA  = u    + (size_t)cA * NT;
    const float* uB  = u    + (size_t)cB * NT;
    const float* ysA = yseq + (size_t)cA * NT * 9;
    const float* ysB = yseq + (size_t)cB * NT * 9;
    const float* usA = useq + (size_t)cA * NT * 3;
    const float* usB = useq + (size_t)cB * NT * 3;
    float*       oA  = out  + (size_t)cA * NT * 3;
    float*       oB  = out  + (size_t)cB * NT * 3;

    f32x2 x0p = (f32x2)0.f, x1p = (f32x2)0.f, x2p = (f32x2)0.f;

    f32x2 basep = (f32x2)0.f;
    float utA = 0.f, utB = 0.f;

    auto rhs = [&](f32x2 X0, f32x2 X1, f32x2 X2,
                   f32x2& D0, f32x2& D1, f32x2& D2) {
        // layer1 (pk): only x-part varies per RK stage
        f32x2 h1 = basep + X0 * w1x[0] + X1 * w1x[1] + X2 * w1x[2];
        h1.x = fmaxf(h1.x, 0.f);
        h1.y = fmaxf(h1.y, 0.f);
        h1A[wave][lane] = h1.x;
        h1B[wave][lane] = h1.y;
        __builtin_amdgcn_wave_barrier();
        // layer2: pk over consecutive-j pairs, per chain; 2 accums/chain
        f32x2 aA0 = (f32x2)0.f, aA1 = (f32x2)0.f;
        f32x2 aB0 = (f32x2)0.f, aB1 = (f32x2)0.f;
        const float4* hA4 = reinterpret_cast<const float4*>(&h1A[wave][0]);
        const float4* hB4 = reinterpret_cast<const float4*>(&h1B[wave][0]);
        #pragma unroll
        for (int jj = 0; jj < 16; ++jj) {
            float4 qa = hA4[jj];
            aA0 += (f32x2){qa.x, qa.y} * w2p[2 * jj];
            aA1 += (f32x2){qa.z, qa.w} * w2p[2 * jj + 1];
            float4 qb = hB4[jj];
            aB0 += (f32x2){qb.x, qb.y} * w2p[2 * jj];
            aB1 += (f32x2){qb.z, qb.w} * w2p[2 * jj + 1];
        }
        __builtin_amdgcn_wave_barrier();
        float h2A = fmaxf(b2h + ((aA0.x + aA1.x) + (aA0.y + aA1.y)), 0.f);
        float h2B = fmaxf(b2h + ((aB0.x + aB1.x) + (aB0.y + aB1.y)), 0.f);
        // layer3 partials; 6 interleaved DPP butterflies (VALU pipe)
        float q0 = h2A * w3r[0], q1 = h2B * w3r[0];
        float q2 = h2A * w3r[1], q3 = h2B * w3r[1];
        float q4 = h2A * w3r[2], q5 = h2B * w3r[2];
        #define BLVL(CT, RM, BM)                                         \
            q0 = dpp_add<CT, RM, BM>(q0); q1 = dpp_add<CT, RM, BM>(q1);  \
            q2 = dpp_add<CT, RM, BM>(q2); q3 = dpp_add<CT, RM, BM>(q3);  \
            q4 = dpp_add<CT, RM, BM>(q4); q5 = dpp_add<CT, RM, BM>(q5);
        BLVL(0x111, 0xf, 0xf)   // row_shr:1
        BLVL(0x112, 0xf, 0xf)   // row_shr:2
        BLVL(0x114, 0xf, 0xe)   // row_shr:4
        BLVL(0x118, 0xf, 0xc)   // row_shr:8
        BLVL(0x142, 0xa, 0xf)   // row_bcast:15
        BLVL(0x143, 0xc, 0xf)   // row_bcast:31
        #undef BLVL
        float sA0 = rl63(q0), sB0 = rl63(q1);
        float sA1 = rl63(q2), sB1 = rl63(q3);
        float sA2 = rl63(q4), sB2 = rl63(q5);
        // _fg per half (K1=1, BETA=16, F=0.1, VR=1); fast sqrt/rcp (~1ulp)
        float sa = __builtin_amdgcn_sqrtf(fmaf(16.f, X0.x, 1.f));
        float ra = __builtin_amdgcn_rcpf(1.f + sa);
        float f0a = fmaf(0.1f, utA - X0.x, -X0.x);
        float f1a = fmaf(0.5f * X0.x * (sa - 1.f), ra, -0.1f * X1.x);
        float f2a = fmaf(2.f * X0.x, ra, -0.1f * X2.x);
        float sb = __builtin_amdgcn_sqrtf(fmaf(16.f, X0.y, 1.f));
        float rb = __builtin_amdgcn_rcpf(1.f + sb);
        float f0b = fmaf(0.1f, utB - X0.y, -X0.y);
        float f1b = fmaf(0.5f * X0.y * (sb - 1.f), rb, -0.1f * X1.y);
        float f2b = fmaf(2.f * X0.y, rb, -0.1f * X2.y);
        D0 = (f32x2){(f0a + b30) + sA0, (f0b + b30) + sB0};
        D1 = (f32x2){(f1a + b31) + sA1, (f1b + b31) + sB1};
        D2 = (f32x2){(f2a + b32) + sA2, (f2b + b32) + sB2};
    };

    for (int t = 0; t < NT; ++t) {
        // output = state at entry of step t
        if (lane < 3) {
            float v = (lane == 0) ? x0p.x : (lane == 1 ? x1p.x : x2p.x);
            oA[t * 3 + lane] = v;
        }
        {
            unsigned l2 = (unsigned)(lane - 16);
            if (l2 < 3u) {
                float v = (l2 == 0) ? x0p.y : (l2 == 1 ? x1p.y : x2p.y);
                oB[t * 3 + l2] = v;
            }
        }

        utA = uA[t]; utB = uB[t];
        float bA = b1h, bB = b1h;
        #pragma unroll
        for (int i = 0; i < 9; ++i) {
            bA = fmaf(ysA[t * 9 + i], w1y[i], bA);
            bB = fmaf(ysB[t * 9 + i], w1y[i], bB);
        }
        #pragma unroll
        for (int i = 0; i < 3; ++i) {
            bA = fmaf(usA[t * 3 + i], w1u[i], bA);
            bB = fmaf(usB[t * 3 + i], w1u[i], bB);
        }
        basep = (f32x2){bA, bB};

        f32x2 k0, k1, k2, a0, a1, a2;
        rhs(x0p, x1p, x2p, k0, k1, k2);                       // k1
        a0 = k0; a1 = k1; a2 = k2;
        rhs(x0p + 0.005f * k0, x1p + 0.005f * k1,             // k2
            x2p + 0.005f * k2, k0, k1, k2);
        a0 += 2.f * k0; a1 += 2.f * k1; a2 += 2.f * k2;
        rhs(x0p + 0.005f * k0, x1p + 0.005f * k1,             // k3
            x2p + 0.005f * k2, k0, k1, k2);
        a0 += 2.f * k0; a1 += 2.f * k1; a2 += 2.f * k2;
        rhs(x0p + 0.01f * k0, x1p + 0.01f * k1,               // k4
            x2p + 0.01f * k2, k0, k1, k2);
        a0 += k0; a1 += k1; a2 += k2;

        const float c = 0.01f / 6.f;
        x0p += c * a0;
        x1p += c * a1;
        x2p += c * a2;
    }
}

extern "C" void kernel_launch(void* const* d_in, const int* in_sizes, int n_in,
                              void* d_out, int out_size, void* d_ws, size_t ws_size,
                              hipStream_t stream) {
    const float* u    = (const float*)d_in[0];
    const float* yseq = (const float*)d_in[1];
    const float* useq = (const float*)d_in[2];
    const float* W1   = (const float*)d_in[3];
    const float* b1   = (const float*)d_in[4];
    const float* W2   = (const float*)d_in[5];
    const float* b2   = (const float*)d_in[6];
    const float* W3   = (const float*)d_in[7];
    const float* b3   = (const float*)d_in[8];
    float* out = (float*)d_out;

    // 4096 chains / 2 per wave = 2048 waves; 4 waves/block -> 512 blocks
    tworeac_kernel<<<NB / 8, 256, 0, stream>>>(u, yseq, useq, W1, b1, W2, b2,
                                               W3, b3, out);
}

// Round 7
// 1109.292 us; speedup vs baseline: 1.2856x; 1.2856x over previous
//
#include <hip/hip_runtime.h>

#define NB 4096
#define NT 256

typedef float f32x2 __attribute__((ext_vector_type(2)));

// One wave = ONE chain (4096 waves = 4/SIMD -> latency well hidden, r2-r4
// ran ~106% VALUBusy). Layer2 packed over j-PAIRS within the chain:
// 32 v_pk_fma_f32 instead of 64 v_fma_f32 — halves the dominant VALU cost
// without halving the wave count (r5's mistake: 2 chains/wave -> 2048 waves
// -> 2/SIMD -> VALUBusy 56%, latency-bound).
// Weights as f32x2 pairs w2p[32] (the exact form that made the allocator
// finally keep them resident in r5: VGPR_Count 64 -> 84).
// h1 broadcast via LDS uniform-address b128 reads (conflict-free, pairs of
// the quad feed pk_fma directly as aligned register pairs).
// Layer3 reduction: 3 interleaved DPP butterflies (VALU pipe) + readlane.

template <int ctrl, int rm, int bm>
__device__ __forceinline__ float dpp_add(float v) {
    int m = __builtin_amdgcn_update_dpp(0, __builtin_bit_cast(int, v),
                                        ctrl, rm, bm, true);
    return v + __builtin_bit_cast(float, m);
}

__device__ __forceinline__ float rl63(float v) {
    return __builtin_bit_cast(float,
        __builtin_amdgcn_readlane(__builtin_bit_cast(int, v), 63));
}

__global__ __attribute__((amdgpu_flat_work_group_size(256, 256),
                          amdgpu_waves_per_eu(2, 4)))
void tworeac_kernel(
    const float* __restrict__ u, const float* __restrict__ yseq,
    const float* __restrict__ useq, const float* __restrict__ W1,
    const float* __restrict__ b1, const float* __restrict__ W2,
    const float* __restrict__ b2, const float* __restrict__ W3,
    const float* __restrict__ b3, float* __restrict__ out)
{
    const int lane = threadIdx.x & 63;
    const int wave = threadIdx.x >> 6;
    const int b = blockIdx.x * 4 + wave;

    __shared__ float h1s[4][64];

    // ---- weights into registers (lane owns hidden column h = lane) ----
    f32x2 w2p[32];   // {W2[2m][lane], W2[2m+1][lane]} — j-pair per pk_fma
    #pragma unroll
    for (int m = 0; m < 32; ++m)
        w2p[m] = (f32x2){W2[(2 * m) * 64 + lane], W2[(2 * m + 1) * 64 + lane]};
    float w1x[3], w1y[9], w1u[3], w3r[3];
    #pragma unroll
    for (int i = 0; i < 3; ++i) w1x[i] = W1[i * 64 + lane];
    #pragma unroll
    for (int i = 0; i < 9; ++i) w1y[i] = W1[(3 + i) * 64 + lane];
    #pragma unroll
    for (int i = 0; i < 3; ++i) w1u[i] = W1[(12 + i) * 64 + lane];
    #pragma unroll
    for (int k = 0; k < 3; ++k) w3r[k] = W3[lane * 3 + k];
    const float b1h = b1[lane];
    const float b2h = b2[lane];
    const float b30 = b3[0], b31 = b3[1], b32 = b3[2];

    const float* ub  = u    + (size_t)b * NT;
    const float* ysb = yseq + (size_t)b * NT * 9;
    const float* usb = useq + (size_t)b * NT * 3;
    float*       ob  = out  + (size_t)b * NT * 3;

    float x0 = 0.f, x1 = 0.f, x2 = 0.f;
    float base1 = 0.f, ut = 0.f;

    auto rhs = [&](float xa, float xd, float xc,
                   float& d0, float& d1, float& d2) {
        // layer1 (scalar; only x-part varies per RK stage)
        float h1 = fmaf(xa, w1x[0], fmaf(xd, w1x[1], fmaf(xc, w1x[2], base1)));
        h1 = fmaxf(h1, 0.f);
        h1s[wave][lane] = h1;
        __builtin_amdgcn_wave_barrier();
        // layer2: 32 pk_fma over j-pairs; 4 independent f32x2 accumulators
        f32x2 a0 = (f32x2)0.f, a1 = (f32x2)0.f;
        f32x2 a2 = (f32x2)0.f, a3 = (f32x2)0.f;
        const float4* h4 = reinterpret_cast<const float4*>(&h1s[wave][0]);
        #pragma unroll
        for (int jj = 0; jj < 8; ++jj) {
            float4 qa = h4[2 * jj];
            a0 += (f32x2){qa.x, qa.y} * w2p[4 * jj + 0];
            a1 += (f32x2){qa.z, qa.w} * w2p[4 * jj + 1];
            float4 qb = h4[2 * jj + 1];
            a2 += (f32x2){qb.x, qb.y} * w2p[4 * jj + 2];
            a3 += (f32x2){qb.z, qb.w} * w2p[4 * jj + 3];
        }
        __builtin_amdgcn_wave_barrier();
        f32x2 sp = (a0 + a1) + (a2 + a3);
        float h2 = fmaxf(b2h + (sp.x + sp.y), 0.f);
        // layer3 partials; 3 interleaved DPP butterflies
        float q0 = h2 * w3r[0];
        float q1 = h2 * w3r[1];
        float q2 = h2 * w3r[2];
        #define BLVL(CT, RM, BM)                                        \
            q0 = dpp_add<CT, RM, BM>(q0);                               \
            q1 = dpp_add<CT, RM, BM>(q1);                               \
            q2 = dpp_add<CT, RM, BM>(q2);
        BLVL(0x111, 0xf, 0xf)   // row_shr:1
        BLVL(0x112, 0xf, 0xf)   // row_shr:2
        BLVL(0x114, 0xf, 0xe)   // row_shr:4
        BLVL(0x118, 0xf, 0xc)   // row_shr:8
        BLVL(0x142, 0xa, 0xf)   // row_bcast:15
        BLVL(0x143, 0xc, 0xf)   // row_bcast:31
        #undef BLVL
        float s0 = rl63(q0), s1 = rl63(q1), s2 = rl63(q2);
        // _fg (K1=1, BETA=16, F=0.1, VR=1); fast sqrt/rcp (~1 ulp)
        float s = __builtin_amdgcn_sqrtf(fmaf(16.f, xa, 1.f));
        float r = __builtin_amdgcn_rcpf(1.f + s);
        d0 = fmaf(0.1f, ut - xa, -xa) + (s0 + b30);
        d1 = fmaf(0.5f * xa * (s - 1.f), r, -0.1f * xd) + (s1 + b31);
        d2 = fmaf(2.f * xa, r, -0.1f * xc) + (s2 + b32);
    };

    for (int t = 0; t < NT; ++t) {
        // output = state at entry of step t
        if (lane < 3) {
            float v = (lane == 0) ? x0 : (lane == 1 ? x1 : x2);
            ob[t * 3 + lane] = v;
        }

        ut = ub[t];
        base1 = b1h;
        #pragma unroll
        for (int i = 0; i < 9; ++i) base1 = fmaf(ysb[t * 9 + i], w1y[i], base1);
        #pragma unroll
        for (int i = 0; i < 3; ++i) base1 = fmaf(usb[t * 3 + i], w1u[i], base1);

        float k0, k1v, k2v, a0, a1, a2;
        rhs(x0, x1, x2, k0, k1v, k2v);                       // k1
        a0 = k0; a1 = k1v; a2 = k2v;
        rhs(fmaf(0.005f, k0, x0), fmaf(0.005f, k1v, x1),     // k2
            fmaf(0.005f, k2v, x2), k0, k1v, k2v);
        a0 = fmaf(2.f, k0, a0); a1 = fmaf(2.f, k1v, a1); a2 = fmaf(2.f, k2v, a2);
        rhs(fmaf(0.005f, k0, x0), fmaf(0.005f, k1v, x1),     // k3
            fmaf(0.005f, k2v, x2), k0, k1v, k2v);
        a0 = fmaf(2.f, k0, a0); a1 = fmaf(2.f, k1v, a1); a2 = fmaf(2.f, k2v, a2);
        rhs(fmaf(0.01f, k0, x0), fmaf(0.01f, k1v, x1),       // k4
            fmaf(0.01f, k2v, x2), k0, k1v, k2v);
        a0 += k0; a1 += k1v; a2 += k2v;

        const float c = 0.01f / 6.f;
        x0 = fmaf(c, a0, x0);
        x1 = fmaf(c, a1, x1);
        x2 = fmaf(c, a2, x2);
    }
}

extern "C" void kernel_launch(void* const* d_in, const int* in_sizes, int n_in,
                              void* d_out, int out_size, void* d_ws, size_t ws_size,
                              hipStream_t stream) {
    const float* u    = (const float*)d_in[0];
    const float* yseq = (const float*)d_in[1];
    const float* useq = (const float*)d_in[2];
    const float* W1   = (const float*)d_in[3];
    const float* b1   = (const float*)d_in[4];
    const float* W2   = (const float*)d_in[5];
    const float* b2   = (const float*)d_in[6];
    const float* W3   = (const float*)d_in[7];
    const float* b3   = (const float*)d_in[8];
    float* out = (float*)d_out;

    // 4096 chains, 1 per wave, 4 waves/block -> 1024 blocks (4 blocks/CU)
    tworeac_kernel<<<NB / 4, 256, 0, stream>>>(u, yseq, useq, W1, b1, W2, b2,
                                               W3, b3, out);
}